// Round 4
// baseline (174.826 us; speedup 1.0000x reference)
//
#include <hip/hip_runtime.h>
#include <hip/hip_bf16.h>
#include <math.h>

// Sizes fixed by the reference.
#define T_PTS 400
#define D_OUT 10000
#define L12   1200   // len(features1) == len(features2)
#define L3    800    // len(features3)
#define FEAT_TOTAL (L12 + L12 + L3 + 3)   // 3203 floats in d_ws

// Padded LDS feature layout (zero-padded so masked-out lanes do +0.0 exactly):
//   fs[0    .. 1280)  features1 (1200 valid, 80 zero)
//   fs[1280 .. 2560)  features2 (1200 valid, 80 zero)
//   fs[2560 .. 3584)  features3 (800 valid, 224 zero)
//   fs[3584 .. 3587)  energy
#define F1_OFF 0
#define F2_OFF 1280
#define F3_OFF 2560
#define E_OFF  3584
#define FS_TOTAL 3587

// ---------------------------------------------------------------------------
// Kernel 1: build the feature vector from input (T,4) into ws.
// ---------------------------------------------------------------------------
__global__ __launch_bounds__(512)
void hdc_features_kernel(const float* __restrict__ in, float* __restrict__ feat) {
    __shared__ float red[3][8];
    const int tid = threadIdx.x;          // 0..511
    float ex = 0.f, ey = 0.f, ez = 0.f;

    if (tid < T_PTS) {
        const float4 cur = reinterpret_cast<const float4*>(in)[tid];
        const float x = cur.y, y = cur.z, z = cur.w;
        feat[tid]        = x;
        feat[400 + tid]  = y;
        feat[800 + tid]  = z;
        feat[2400 + tid] = sqrtf(x * x + y * y + z * z);
        ex = x * x; ey = y * y; ez = z * z;

        float jx = 0.f, jy = 0.f, jz = 0.f;
        if (tid > 0) {
            const float4 prev = reinterpret_cast<const float4*>(in)[tid - 1];
            const float dt = cur.x - prev.x;           // t0 offset cancels
            const float inv = 1.0f / dt;
            jx = (x - prev.y) * inv;
            jy = (y - prev.z) * inv;
            jz = (z - prev.w) * inv;
        }
        feat[1200 + tid] = jx;
        feat[1600 + tid] = jy;
        feat[2000 + tid] = jz;
        feat[2800 + tid] = sqrtf(jx * jx + jy * jy + jz * jz);
    }

    #pragma unroll
    for (int off = 32; off; off >>= 1) {
        ex += __shfl_down(ex, off, 64);
        ey += __shfl_down(ey, off, 64);
        ez += __shfl_down(ez, off, 64);
    }
    const int wave = tid >> 6, lane = tid & 63;
    if (lane == 0) { red[0][wave] = ex; red[1][wave] = ey; red[2][wave] = ez; }
    __syncthreads();
    if (tid == 0) {
        float sx = 0.f, sy = 0.f, sz = 0.f;
        #pragma unroll
        for (int w = 0; w < 8; ++w) { sx += red[0][w]; sy += red[1][w]; sz += red[2][w]; }
        const float invT = 1.0f / (float)T_PTS;
        feat[3200] = sx * invT;
        feat[3201] = sy * invT;
        feat[3202] = sz * invT;
    }
}

// ---------------------------------------------------------------------------
// Kernel 2: fused 4-way GEMV + tanh epilogue.
// 1250 blocks x 256 threads (4 waves); wave w owns rows d0 = 8b+2w, d1 = d0+1.
// FULLY UNROLLED: all 28 float4 weight loads are register-staged before the
// FMA cluster so the scheduler issues them back-to-back (latency-bound fix;
// round-3 counters showed VALUBusy 10% / HBM 17% / MfmaUtil 0 = latency).
// Tail iterations are exec-masked (lane<44 for L12 iter 4, lane<8 for L3
// iter 3); LDS features are zero-padded so masked contributions are exact 0.
// __launch_bounds__(256,4): cap VGPR at 128 -> >=4 waves/SIMD resident.
// ---------------------------------------------------------------------------
__global__ __launch_bounds__(256, 4)
void hdc_gemv_kernel(const float* __restrict__ W1, const float* __restrict__ b1,
                     const float* __restrict__ W2, const float* __restrict__ b2,
                     const float* __restrict__ W3, const float* __restrict__ b3,
                     const float* __restrict__ W4, const float* __restrict__ b4,
                     const float* __restrict__ feat, float* __restrict__ out) {
    __shared__ float fs[FS_TOTAL];
    const int tid = threadIdx.x;

    // Stage + zero-pad features.
    for (int k = tid; k < 1280; k += 256) {
        fs[F1_OFF + k] = (k < L12) ? feat[k] : 0.f;
        fs[F2_OFF + k] = (k < L12) ? feat[L12 + k] : 0.f;
    }
    for (int k = tid; k < 1024; k += 256)
        fs[F3_OFF + k] = (k < L3) ? feat[2400 + k] : 0.f;
    if (tid < 3) fs[E_OFF + tid] = feat[3200 + tid];
    __syncthreads();

    const int wave = tid >> 6, lane = tid & 63;
    const int d0 = blockIdx.x * 8 + wave * 2;   // 1250*8 == 10000, no tail
    const int d1 = d0 + 1;
    const int k0 = lane * 4;

    const float* __restrict__ w1a = W1 + (size_t)d0 * L12;
    const float* __restrict__ w1b = W1 + (size_t)d1 * L12;
    const float* __restrict__ w2a = W2 + (size_t)d0 * L12;
    const float* __restrict__ w2b = W2 + (size_t)d1 * L12;
    const float* __restrict__ w3a = W3 + (size_t)d0 * L3;
    const float* __restrict__ w3b = W3 + (size_t)d1 * L3;

    const bool v12 = (lane < 44);   // L12 iteration 4: k0+1024 < 1200
    const bool v3  = (lane < 8);    // L3  iteration 3: k0+768  < 800
    const float4 z4 = make_float4(0.f, 0.f, 0.f, 0.f);

    // ---- Issue ALL weight loads (register-staged, compile-time indexed) ----
    float4 r1a[5], r1b[5], r2a[5], r2b[5], r3a[4], r3b[4];
    #pragma unroll
    for (int i = 0; i < 4; ++i) {
        const int k = k0 + 256 * i;
        r1a[i] = *reinterpret_cast<const float4*>(w1a + k);
        r1b[i] = *reinterpret_cast<const float4*>(w1b + k);
        r2a[i] = *reinterpret_cast<const float4*>(w2a + k);
        r2b[i] = *reinterpret_cast<const float4*>(w2b + k);
    }
    {
        const int k = k0 + 1024;
        r1a[4] = v12 ? *reinterpret_cast<const float4*>(w1a + k) : z4;
        r1b[4] = v12 ? *reinterpret_cast<const float4*>(w1b + k) : z4;
        r2a[4] = v12 ? *reinterpret_cast<const float4*>(w2a + k) : z4;
        r2b[4] = v12 ? *reinterpret_cast<const float4*>(w2b + k) : z4;
    }
    #pragma unroll
    for (int i = 0; i < 3; ++i) {
        const int k = k0 + 256 * i;
        r3a[i] = *reinterpret_cast<const float4*>(w3a + k);
        r3b[i] = *reinterpret_cast<const float4*>(w3b + k);
    }
    {
        const int k = k0 + 768;
        r3a[3] = v3 ? *reinterpret_cast<const float4*>(w3a + k) : z4;
        r3b[3] = v3 ? *reinterpret_cast<const float4*>(w3b + k) : z4;
    }

    // ---- FMA cluster (features from zero-padded LDS) ----
    float a1a = 0.f, a1b = 0.f, a2a = 0.f, a2b = 0.f, a3a = 0.f, a3b = 0.f;
    #pragma unroll
    for (int i = 0; i < 5; ++i) {
        const int k = k0 + 256 * i;
        const float4 s1 = *reinterpret_cast<const float4*>(&fs[F1_OFF + k]);
        const float4 s2 = *reinterpret_cast<const float4*>(&fs[F2_OFF + k]);
        a1a += r1a[i].x * s1.x + r1a[i].y * s1.y + r1a[i].z * s1.z + r1a[i].w * s1.w;
        a1b += r1b[i].x * s1.x + r1b[i].y * s1.y + r1b[i].z * s1.z + r1b[i].w * s1.w;
        a2a += r2a[i].x * s2.x + r2a[i].y * s2.y + r2a[i].z * s2.z + r2a[i].w * s2.w;
        a2b += r2b[i].x * s2.x + r2b[i].y * s2.y + r2b[i].z * s2.z + r2b[i].w * s2.w;
    }
    #pragma unroll
    for (int i = 0; i < 4; ++i) {
        const int k = k0 + 256 * i;
        const float4 s3 = *reinterpret_cast<const float4*>(&fs[F3_OFF + k]);
        a3a += r3a[i].x * s3.x + r3a[i].y * s3.y + r3a[i].z * s3.z + r3a[i].w * s3.w;
        a3b += r3b[i].x * s3.x + r3b[i].y * s3.y + r3b[i].z * s3.z + r3b[i].w * s3.w;
    }

    // wave64 reduction (6 accumulators)
    #pragma unroll
    for (int off = 32; off; off >>= 1) {
        a1a += __shfl_down(a1a, off, 64);
        a1b += __shfl_down(a1b, off, 64);
        a2a += __shfl_down(a2a, off, 64);
        a2b += __shfl_down(a2b, off, 64);
        a3a += __shfl_down(a3a, off, 64);
        a3b += __shfl_down(a3b, off, 64);
    }

    if (lane == 0) {
        const float e0 = fs[E_OFF], e1 = fs[E_OFF + 1], e2 = fs[E_OFF + 2];
        const float hv1a = tanhf(a1a + b1[d0]);
        const float hv2a = tanhf(a2a + b2[d0]);
        const float hv3a = tanhf(a3a + b3[d0]);
        const float hv4a = tanhf(W4[(size_t)d0 * 3 + 0] * e0 +
                                 W4[(size_t)d0 * 3 + 1] * e1 +
                                 W4[(size_t)d0 * 3 + 2] * e2 + b4[d0]);
        out[d0] = tanhf(hv1a * hv4a + hv2a + hv3a);

        const float hv1b = tanhf(a1b + b1[d1]);
        const float hv2b = tanhf(a2b + b2[d1]);
        const float hv3b = tanhf(a3b + b3[d1]);
        const float hv4b = tanhf(W4[(size_t)d1 * 3 + 0] * e0 +
                                 W4[(size_t)d1 * 3 + 1] * e1 +
                                 W4[(size_t)d1 * 3 + 2] * e2 + b4[d1]);
        out[d1] = tanhf(hv1b * hv4b + hv2b + hv3b);
    }
}

extern "C" void kernel_launch(void* const* d_in, const int* in_sizes, int n_in,
                              void* d_out, int out_size, void* d_ws, size_t ws_size,
                              hipStream_t stream) {
    const float* input = (const float*)d_in[0];
    const float* W1 = (const float*)d_in[1];
    const float* b1 = (const float*)d_in[2];
    const float* W2 = (const float*)d_in[3];
    const float* b2 = (const float*)d_in[4];
    const float* W3 = (const float*)d_in[5];
    const float* b3 = (const float*)d_in[6];
    const float* W4 = (const float*)d_in[7];
    const float* b4 = (const float*)d_in[8];
    float* out = (float*)d_out;
    float* feat = (float*)d_ws;

    hdc_features_kernel<<<1, 512, 0, stream>>>(input, feat);
    hdc_gemv_kernel<<<D_OUT / 8, 256, 0, stream>>>(W1, b1, W2, b2, W3, b3,
                                                   W4, b4, feat, out);
}

// Round 7
// 163.780 us; speedup vs baseline: 1.0674x; 1.0674x over previous
//
#include <hip/hip_runtime.h>
#include <hip/hip_bf16.h>
#include <math.h>

// Sizes fixed by the reference.
#define T_PTS 400
#define D_OUT 10000
#define L12   1200   // len(features1) == len(features2)
#define L3    800    // len(features3)
#define ROW   3200   // concatenated [W1row | W2row | W3row]
#define FEAT_TOTAL (ROW + 3)

// ---------------------------------------------------------------------------
// Kernel 1: build the feature vector from input (T,4) into ws:
//   [0,1200) f1 = [x,y,z], [1200,2400) f2 = jerks, [2400,3200) f3 = mags,
//   [3200,3203) energy
// ---------------------------------------------------------------------------
__global__ __launch_bounds__(512)
void hdc_features_kernel(const float* __restrict__ in, float* __restrict__ feat) {
    __shared__ float red[3][8];
    const int tid = threadIdx.x;          // 0..511
    float ex = 0.f, ey = 0.f, ez = 0.f;

    if (tid < T_PTS) {
        const float4 cur = reinterpret_cast<const float4*>(in)[tid];
        const float x = cur.y, y = cur.z, z = cur.w;
        feat[tid]        = x;
        feat[400 + tid]  = y;
        feat[800 + tid]  = z;
        feat[2400 + tid] = sqrtf(x * x + y * y + z * z);
        ex = x * x; ey = y * y; ez = z * z;

        float jx = 0.f, jy = 0.f, jz = 0.f;
        if (tid > 0) {
            const float4 prev = reinterpret_cast<const float4*>(in)[tid - 1];
            const float dt = cur.x - prev.x;           // t0 offset cancels
            const float inv = 1.0f / dt;
            jx = (x - prev.y) * inv;
            jy = (y - prev.z) * inv;
            jz = (z - prev.w) * inv;
        }
        feat[1200 + tid] = jx;
        feat[1600 + tid] = jy;
        feat[2000 + tid] = jz;
        feat[2800 + tid] = sqrtf(jx * jx + jy * jy + jz * jz);
    }

    #pragma unroll
    for (int off = 32; off; off >>= 1) {
        ex += __shfl_down(ex, off, 64);
        ey += __shfl_down(ey, off, 64);
        ez += __shfl_down(ez, off, 64);
    }
    const int wave = tid >> 6, lane = tid & 63;
    if (lane == 0) { red[0][wave] = ex; red[1][wave] = ey; red[2][wave] = ez; }
    __syncthreads();
    if (tid == 0) {
        float sx = 0.f, sy = 0.f, sz = 0.f;
        #pragma unroll
        for (int w = 0; w < 8; ++w) { sx += red[0][w]; sy += red[1][w]; sz += red[2][w]; }
        const float invT = 1.0f / (float)T_PTS;
        feat[3200] = sx * invT;
        feat[3201] = sy * invT;
        feat[3202] = sz * invT;
    }
}

// ---------------------------------------------------------------------------
// Kernel 2: fused 4-way GEMV + tanh epilogue.
// 2500 blocks x 256 threads (4 waves). Wave w owns output row d = 4b + w and
// loads the ENTIRE concatenated row [W1row|W2row|W3row] (3200 floats) as
// exactly 12 float4 + 1 float2 per lane, issued back-to-back BEFORE the
// feature-staging barrier (the barrier's vmcnt drain hides weight latency
// under LDS staging). 48 staging VGPRs -> register-resident (R4 spilled at
// 112). Steps 4 and 9 straddle matrix boundaries; branchless per-lane select.
// Lane-0 epilogue scalars are prefetched before the shuffle reduction so
// their latency hides under the 6 shuffle steps.
// ---------------------------------------------------------------------------
__global__ __launch_bounds__(256)
void hdc_gemv_kernel(const float* __restrict__ W1, const float* __restrict__ b1,
                     const float* __restrict__ W2, const float* __restrict__ b2,
                     const float* __restrict__ W3, const float* __restrict__ b3,
                     const float* __restrict__ W4, const float* __restrict__ b4,
                     const float* __restrict__ feat, float* __restrict__ out) {
    __shared__ __align__(16) float g[FEAT_TOTAL];
    const int tid = threadIdx.x;
    const int wave = tid >> 6, lane = tid & 63;
    const int d = blockIdx.x * 4 + wave;        // 2500*4 == 10000, no tail
    const int c0 = lane * 4;                    // 0..252

    const float* __restrict__ w1 = W1 + (size_t)d * L12;
    const float* __restrict__ w2 = W2 + (size_t)d * L12;
    const float* __restrict__ w3 = W3 + (size_t)d * L3;

    // ---- Issue all 13 weight loads back-to-back (register staged) ----
    float4 r[12];
    #pragma unroll
    for (int i = 0; i < 12; ++i) {
        const int k = 256 * i + c0;             // element in concatenated row
        const float* p;
        if (i < 4)       p = w1 + k;                                  // pure W1
        else if (i == 4) p = (k < L12) ? (w1 + k) : (w2 + (k - L12)); // mixed
        else if (i < 9)  p = w2 + (k - L12);                          // pure W2
        else if (i == 9) p = (k < 2400) ? (w2 + (k - L12)) : (w3 + (k - 2400));
        else             p = w3 + (k - 2400);                         // pure W3
        r[i] = *reinterpret_cast<const float4*>(p);
    }
    const float2 rt = *reinterpret_cast<const float2*>(w3 + (3072 - 2400) + 2 * lane);

    // ---- Stage features into LDS (overlaps with weight-load latency) ----
    {
        float4* g4 = reinterpret_cast<float4*>(g);
        const float4* feat4 = reinterpret_cast<const float4*>(feat);
        for (int i = tid; i < ROW / 4; i += 256) g4[i] = feat4[i];
        if (tid == 0) { g[3200] = feat[3200]; g[3201] = feat[3201]; g[3202] = feat[3202]; }
    }
    __syncthreads();   // drains vmcnt: weights now in regs, features in LDS

    // ---- FMA cluster ----
    float acc1 = 0.f, acc2 = 0.f, acc3 = 0.f;
    #pragma unroll
    for (int i = 0; i < 12; ++i) {
        const int k = 256 * i + c0;
        const float4 s = *reinterpret_cast<const float4*>(&g[k]);
        const float t = r[i].x * s.x + r[i].y * s.y + r[i].z * s.z + r[i].w * s.w;
        if (i < 4)       acc1 += t;
        else if (i == 4) { acc1 += (k < L12) ? t : 0.f; acc2 += (k < L12) ? 0.f : t; }
        else if (i < 9)  acc2 += t;
        else if (i == 9) { acc2 += (k < 2400) ? t : 0.f; acc3 += (k < 2400) ? 0.f : t; }
        else             acc3 += t;
    }
    {
        const int k = 3072 + 2 * lane;
        acc3 += rt.x * g[k] + rt.y * g[k + 1];
    }

    // ---- Prefetch epilogue scalars (lane 0 only uses them after reduce) ----
    float bb1 = 0.f, bb2 = 0.f, bb3 = 0.f, bb4 = 0.f, w40 = 0.f, w41 = 0.f, w42 = 0.f;
    if (lane == 0) {
        bb1 = b1[d]; bb2 = b2[d]; bb3 = b3[d]; bb4 = b4[d];
        w40 = W4[(size_t)d * 3 + 0];
        w41 = W4[(size_t)d * 3 + 1];
        w42 = W4[(size_t)d * 3 + 2];
    }

    // ---- wave64 reduction (3 accumulators) ----
    #pragma unroll
    for (int off = 32; off; off >>= 1) {
        acc1 += __shfl_down(acc1, off, 64);
        acc2 += __shfl_down(acc2, off, 64);
        acc3 += __shfl_down(acc3, off, 64);
    }

    if (lane == 0) {
        const float e0 = g[3200], e1 = g[3201], e2 = g[3202];
        const float hv1 = tanhf(acc1 + bb1);
        const float hv2 = tanhf(acc2 + bb2);
        const float hv3 = tanhf(acc3 + bb3);
        const float hv4 = tanhf(w40 * e0 + w41 * e1 + w42 * e2 + bb4);
        out[d] = tanhf(hv1 * hv4 + hv2 + hv3);
    }
}

extern "C" void kernel_launch(void* const* d_in, const int* in_sizes, int n_in,
                              void* d_out, int out_size, void* d_ws, size_t ws_size,
                              hipStream_t stream) {
    const float* input = (const float*)d_in[0];
    const float* W1 = (const float*)d_in[1];
    const float* b1 = (const float*)d_in[2];
    const float* W2 = (const float*)d_in[3];
    const float* b2 = (const float*)d_in[4];
    const float* W3 = (const float*)d_in[5];
    const float* b3 = (const float*)d_in[6];
    const float* W4 = (const float*)d_in[7];
    const float* b4 = (const float*)d_in[8];
    float* out = (float*)d_out;
    float* feat = (float*)d_ws;

    hdc_features_kernel<<<1, 512, 0, stream>>>(input, feat);
    hdc_gemv_kernel<<<D_OUT / 4, 256, 0, stream>>>(W1, b1, W2, b2, W3, b3,
                                                   W4, b4, feat, out);
}